// Round 1
// baseline (11310.306 us; speedup 1.0000x reference)
//
#include <hip/hip_runtime.h>
#include <stdint.h>

#define DD 96
#define VV (96*96*96)   // 884736
#define EPSN 1e-5f

__device__ __forceinline__ float bf2f(uint32_t u_lo16) {
    union { uint32_t i; float f; } x; x.i = u_lo16 << 16; return x.f;
}
__device__ __forceinline__ uint16_t f2bf(float f) {
    union { float f; uint32_t i; } x; x.f = f;
    uint32_t r = x.i + 0x7FFFu + ((x.i >> 16) & 1u);
    return (uint16_t)(r >> 16);
}

// ---------------- weight transpose:  w0 [co][27] -> wT0 [k][co];
// wk [l][co][ci][27] -> wTk [l][k][ci][co] ----------------
__global__ void k_transpose_w(const float* __restrict__ w0, const float* __restrict__ wk,
                              float* __restrict__ wT0, float* __restrict__ wTk) {
    int i = blockIdx.x * 256 + threadIdx.x;
    if (i < 27 * 32) {
        int co = i / 27, k = i % 27;
        wT0[k * 32 + co] = w0[i];
    }
    int j = i - 27 * 32;
    if (j >= 0 && j < 3 * 32 * 32 * 27) {
        int k = j % 27; int t = j / 27;
        int ci = t % 32; t /= 32;
        int co = t % 32; int l = t / 32;
        wTk[((l * 27 + k) * 32 + ci) * 32 + co] = wk[j];
    }
}

// ---------------- conv0: data fp32 [b][v] -> buf0 raw bf16 chan-last [b][v][c],
// plus per-(z,y,b) stat partials ----------------
__global__ __launch_bounds__(256) void k_conv0(const float* __restrict__ data,
        const float* __restrict__ wT0, uint16_t* __restrict__ out,
        float2* __restrict__ spart) {
    const int y = blockIdx.x, z = blockIdx.y, b = blockIdx.z;
    const int t = threadIdx.x, co = t & 31, xs = t >> 5;
    const int xbase = xs * 12;
    __shared__ float in_s[98];
    __shared__ float wpart[4][32][2];

    float w0r[27];
#pragma unroll
    for (int k = 0; k < 27; ++k) w0r[k] = wT0[k * 32 + co];

    float acc[12];
#pragma unroll
    for (int j = 0; j < 12; ++j) acc[j] = 0.f;

    for (int row = 0; row < 9; ++row) {
        int dz = row / 3 - 1, dy = row % 3 - 1;
        int vz = z + dz, vy = y + dy;
        bool rowok = (vz >= 0 && vz < DD && vy >= 0 && vy < DD);
        long long rbase = (long long)b * VV + (long long)(vz * 96 + vy) * 96;
        __syncthreads();
        if (t < 98) {
            float v = 0.f;
            if (rowok && t >= 1 && t <= 96) v = data[rbase + (t - 1)];
            in_s[t] = v;
        }
        __syncthreads();
#pragma unroll
        for (int p = 0; p < 14; ++p) {
            float v = in_s[xbase + p];
#pragma unroll
            for (int dxi = 0; dxi < 3; ++dxi) {
                int j = p - dxi;
                if (j >= 0 && j < 12) acc[j] += v * w0r[row * 3 + dxi];
            }
        }
    }
    // stats (on raw outputs)
    float s1 = 0.f, s2 = 0.f;
#pragma unroll
    for (int j = 0; j < 12; ++j) { s1 += acc[j]; s2 += acc[j] * acc[j]; }
    s1 += __shfl_xor(s1, 32, 64);
    s2 += __shfl_xor(s2, 32, 64);
    int wv = t >> 6;
    if ((t & 63) < 32) { wpart[wv][co][0] = s1; wpart[wv][co][1] = s2; }
    __syncthreads();
    if (t < 32) {
        float a = 0.f, c2 = 0.f;
#pragma unroll
        for (int w = 0; w < 4; ++w) { a += wpart[w][t][0]; c2 += wpart[w][t][1]; }
        int zone = z * 96 + y;
        spart[(zone * 2 + b) * 32 + t] = make_float2(a, c2);
    }
    // store raw bf16 chan-last
    long long obase = ((long long)b * VV + (long long)(z * 96 + y) * 96 + xbase) * 32 + co;
#pragma unroll
    for (int j = 0; j < 12; ++j) out[obase + (long long)j * 32] = f2bf(acc[j]);
}

// ---------------- stats finalize: spart [9216*2][32] float2 -> mr[bc] = (mean, rsqrt(var+eps)) ---------
__global__ void k_finalize(const float2* __restrict__ spart, float2* __restrict__ mr) {
    const int bc = blockIdx.x, t = threadIdx.x;
    float a = 0.f, s2 = 0.f;
    for (int z = t; z < 9216; z += 256) {
        float2 v = spart[z * 64 + bc];
        a += v.x; s2 += v.y;
    }
#pragma unroll
    for (int m = 1; m < 64; m <<= 1) {
        a  += __shfl_xor(a, m, 64);
        s2 += __shfl_xor(s2, m, 64);
    }
    __shared__ float2 wred[4];
    if ((t & 63) == 0) wred[t >> 6] = make_float2(a, s2);
    __syncthreads();
    if (t == 0) {
        float A = wred[0].x + wred[1].x + wred[2].x + wred[3].x;
        float S = wred[0].y + wred[1].y + wred[2].y + wred[3].y;
        float mean = A / (float)VV;
        float var = S / (float)VV - mean * mean;
        float rs = rsqrtf(fmaxf(var, 0.f) + EPSN);
        mr[bc] = make_float2(mean, rs);
    }
}

// ---------------- convk: in raw bf16 chan-last + prev stats -> out raw bf16 (chan-last or chan-first) ---
template<int CHFIRST>
__global__ __launch_bounds__(256) void k_convk(const uint16_t* __restrict__ in,
        const float2* __restrict__ mrprev, const float* __restrict__ wT,
        uint16_t* __restrict__ out, float2* __restrict__ spart) {
    const int y = blockIdx.x, z = blockIdx.y, b = blockIdx.z;
    const int t = threadIdx.x, co = t & 31, xs = t >> 5;
    const int xbase = xs * 12;
    __shared__ float in_s[98 * 36];
    __shared__ float m_s[32], rs_s[32];
    __shared__ float wpart[4][32][2];

    if (t < 32) { float2 v = mrprev[b * 32 + t]; m_s[t] = v.x; rs_s[t] = v.y; }

    float acc[12];
#pragma unroll
    for (int j = 0; j < 12; ++j) acc[j] = 0.f;

    for (int row = 0; row < 9; ++row) {
        int dz = row / 3 - 1, dy = row % 3 - 1;
        int vz = z + dz, vy = y + dy;
        bool rowok = (vz >= 0 && vz < DD && vy >= 0 && vy < DD);
        long long rbase = (long long)b * VV + (long long)(vz * 96 + vy) * 96;
        __syncthreads();
        // stage one input row: 98 x-positions x 32 ci, normalized+relu, fp32
#pragma unroll
        for (int rr = 0; rr < 2; ++rr) {
            int c = t + rr * 256;
            if (c < 392) {
                int xh = c >> 2, cio = (c & 3) * 8;
                float v[8];
                if (rowok && xh >= 1 && xh <= 96) {
                    const uint16_t* g = in + ((rbase + (xh - 1)) * 32 + cio);
                    uint4 raw = *(const uint4*)g;
                    uint32_t u[4] = {raw.x, raw.y, raw.z, raw.w};
#pragma unroll
                    for (int e = 0; e < 4; ++e) {
                        float lo = bf2f(u[e] & 0xFFFFu);
                        union { uint32_t i; float f; } hi; hi.i = u[e] & 0xFFFF0000u;
                        v[2 * e]     = fmaxf(0.f, (lo   - m_s[cio + 2 * e])     * rs_s[cio + 2 * e]);
                        v[2 * e + 1] = fmaxf(0.f, (hi.f - m_s[cio + 2 * e + 1]) * rs_s[cio + 2 * e + 1]);
                    }
                } else {
#pragma unroll
                    for (int e = 0; e < 8; ++e) v[e] = 0.f;
                }
                float4* dst = (float4*)&in_s[xh * 36 + cio];
                dst[0] = make_float4(v[0], v[1], v[2], v[3]);
                dst[1] = make_float4(v[4], v[5], v[6], v[7]);
            }
        }
        __syncthreads();
        // compute: 4 groups of 8 input channels
        for (int cig = 0; cig < 4; ++cig) {
            float wr[3][8];
            const float* wb = wT + ((row * 3) * 32 + cig * 8) * 32 + co;
#pragma unroll
            for (int dxi = 0; dxi < 3; ++dxi)
#pragma unroll
                for (int e = 0; e < 8; ++e)
                    wr[dxi][e] = wb[(dxi * 32 + e) * 32];
            const float* base = &in_s[xbase * 36 + cig * 8];
#pragma unroll
            for (int p = 0; p < 14; ++p) {
                float4 a4 = *(const float4*)(base + p * 36);
                float4 b4 = *(const float4*)(base + p * 36 + 4);
#pragma unroll
                for (int dxi = 0; dxi < 3; ++dxi) {
                    int j = p - dxi;
                    if (j >= 0 && j < 12) {
                        acc[j] += a4.x * wr[dxi][0] + a4.y * wr[dxi][1]
                                + a4.z * wr[dxi][2] + a4.w * wr[dxi][3]
                                + b4.x * wr[dxi][4] + b4.y * wr[dxi][5]
                                + b4.z * wr[dxi][6] + b4.w * wr[dxi][7];
                    }
                }
            }
        }
    }
    // stats
    float s1 = 0.f, s2 = 0.f;
#pragma unroll
    for (int j = 0; j < 12; ++j) { s1 += acc[j]; s2 += acc[j] * acc[j]; }
    s1 += __shfl_xor(s1, 32, 64);
    s2 += __shfl_xor(s2, 32, 64);
    int wv = t >> 6;
    if ((t & 63) < 32) { wpart[wv][co][0] = s1; wpart[wv][co][1] = s2; }
    __syncthreads();
    if (t < 32) {
        float a = 0.f, c2 = 0.f;
#pragma unroll
        for (int w = 0; w < 4; ++w) { a += wpart[w][t][0]; c2 += wpart[w][t][1]; }
        int zone = z * 96 + y;
        spart[(zone * 2 + b) * 32 + t] = make_float2(a, c2);
    }
    // store raw bf16
    if (CHFIRST) {
        long long obase = (long long)(b * 32 + co) * VV + (long long)(z * 96 + y) * 96 + xbase;
#pragma unroll
        for (int j = 0; j < 12; ++j) out[obase + j] = f2bf(acc[j]);
    } else {
        long long obase = ((long long)b * VV + (long long)(z * 96 + y) * 96 + xbase) * 32 + co;
#pragma unroll
        for (int j = 0; j < 12; ++j) out[obase + (long long)j * 32] = f2bf(acc[j]);
    }
}

// ---------------- normalize prepass (in place): chan-first raw bf16 -> normalized+relu bf16 -----------
__global__ __launch_bounds__(256) void k_prepass(uint16_t* __restrict__ emb,
                                                 const float2* __restrict__ mr) {
    const int bc = blockIdx.y;
    float2 v = mr[bc];
    const float m = v.x, rs = v.y;
    long long idx = (long long)bc * VV + ((long long)blockIdx.x * 256 + threadIdx.x) * 8;
    uint4* p = (uint4*)(emb + idx);
    uint4 raw = *p;
    uint32_t u[4] = {raw.x, raw.y, raw.z, raw.w};
    uint32_t o[4];
#pragma unroll
    for (int e = 0; e < 4; ++e) {
        float lo = bf2f(u[e] & 0xFFFFu);
        union { uint32_t i; float f; } hi; hi.i = u[e] & 0xFFFF0000u;
        float a = fmaxf(0.f, (lo   - m) * rs);
        float b = fmaxf(0.f, (hi.f - m) * rs);
        o[e] = (uint32_t)f2bf(a) | ((uint32_t)f2bf(b) << 16);
    }
    *p = make_uint4(o[0], o[1], o[2], o[3]);
}

// ---------------- pooling: emb_n bf16 chan-first [bc][v] x mask fp32 [r][v] -> zone partials -----------
__global__ __launch_bounds__(256) void k_pool(const uint16_t* __restrict__ emb,
        const float* __restrict__ mask, float* __restrict__ rzone,
        float* __restrict__ mzone) {
    const int t = threadIdx.x;
    const int bcg = t & 15, rg = t >> 4;
    const int bc0 = bcg * 4, r0 = rg * 4;
    const long long cb = (long long)blockIdx.x * 1024;

    float acc[2][4][4];
#pragma unroll
    for (int rb = 0; rb < 2; ++rb)
#pragma unroll
        for (int ri = 0; ri < 4; ++ri)
#pragma unroll
            for (int bi = 0; bi < 4; ++bi) acc[rb][ri][bi] = 0.f;
    float macc[2][4] = {{0.f, 0.f, 0.f, 0.f}, {0.f, 0.f, 0.f, 0.f}};

    for (int it = 0; it < 128; ++it) {
        long long v0 = cb + it * 8;
        float ef[4][8];
#pragma unroll
        for (int bi = 0; bi < 4; ++bi) {
            uint4 raw = *(const uint4*)(emb + (long long)(bc0 + bi) * VV + v0);
            uint32_t u[4] = {raw.x, raw.y, raw.z, raw.w};
#pragma unroll
            for (int e = 0; e < 4; ++e) {
                ef[bi][2 * e] = bf2f(u[e] & 0xFFFFu);
                union { uint32_t i; float f; } hi; hi.i = u[e] & 0xFFFF0000u;
                ef[bi][2 * e + 1] = hi.f;
            }
        }
#pragma unroll
        for (int rb = 0; rb < 2; ++rb) {
#pragma unroll
            for (int ri = 0; ri < 4; ++ri) {
                int r = r0 + rb * 64 + ri;
                float4 m0, m1;
                if (r < 100) {
                    const float* mp = mask + (long long)r * VV + v0;
                    m0 = *(const float4*)mp;
                    m1 = *(const float4*)(mp + 4);
                } else {
                    m0 = make_float4(0.f, 0.f, 0.f, 0.f);
                    m1 = m0;
                }
                if (bcg == 0)
                    macc[rb][ri] += m0.x + m0.y + m0.z + m0.w + m1.x + m1.y + m1.z + m1.w;
#pragma unroll
                for (int bi = 0; bi < 4; ++bi) {
                    acc[rb][ri][bi] += ef[bi][0] * m0.x + ef[bi][1] * m0.y
                                     + ef[bi][2] * m0.z + ef[bi][3] * m0.w
                                     + ef[bi][4] * m1.x + ef[bi][5] * m1.y
                                     + ef[bi][6] * m1.z + ef[bi][7] * m1.w;
                }
            }
        }
    }
#pragma unroll
    for (int rb = 0; rb < 2; ++rb)
#pragma unroll
        for (int ri = 0; ri < 4; ++ri) {
            int r = r0 + rb * 64 + ri;
            if (r < 100) {
#pragma unroll
                for (int bi = 0; bi < 4; ++bi)
                    rzone[((long long)blockIdx.x * 100 + r) * 64 + bc0 + bi] = acc[rb][ri][bi];
                if (bcg == 0) mzone[blockIdx.x * 100 + r] = macc[rb][ri];
            }
        }
}

// ---------------- roi finalize: sum zones, divide by mask sum ----------------
__global__ void k_roifin(const float* __restrict__ rzone, const float* __restrict__ mzone,
                         float* __restrict__ roi) {
    const int r = blockIdx.x, t = threadIdx.x;
    __shared__ float sred[256];
    float ms = 0.f;
    for (int z = t; z < 864; z += 256) ms += mzone[z * 100 + r];
    sred[t] = ms;
    __syncthreads();
    for (int s = 128; s > 0; s >>= 1) {
        if (t < s) sred[t] += sred[t + s];
        __syncthreads();
    }
    float msum = sred[0];
    const int bc = t & 63, zs = t >> 6;
    float a = 0.f;
    for (int z = zs; z < 864; z += 4) a += rzone[((long long)z * 100 + r) * 64 + bc];
    __shared__ float s2[4][64];
    s2[zs][bc] = a;
    __syncthreads();
    if (t < 64) {
        float v = s2[0][t] + s2[1][t] + s2[2][t] + s2[3][t];
        int b = t >> 5, c = t & 31;
        roi[(b * 100 + r) * 32 + c] = v / msum;
    }
}

// ---------------- per-ROI MLPs ----------------
__global__ __launch_bounds__(256) void k_mlp(const float* __restrict__ roi,
        const float* __restrict__ sw1, const float* __restrict__ sb1,
        const float* __restrict__ sw2, const float* __restrict__ sb2,
        const float* __restrict__ pw1, const float* __restrict__ pb1,
        const float* __restrict__ pw2, const float* __restrict__ pb2,
        float* __restrict__ outp) {
    const int r = blockIdx.x, b = blockIdx.y, t = threadIdx.x;
    __shared__ float roi_s[32], h1_s[64], sf_s[32], h2_s[256], part[128];
    if (t < 32) roi_s[t] = roi[(b * 100 + r) * 32 + t];
    __syncthreads();
    if (t < 64) {
        float a = sb1[r * 64 + t];
        for (int c = 0; c < 32; ++c) a += roi_s[c] * sw1[(r * 32 + c) * 64 + t];
        h1_s[t] = fmaxf(a, 0.f);
    }
    __syncthreads();
    if (t < 32) {
        float a = sb2[r * 32 + t];
        for (int h = 0; h < 64; ++h) a += h1_s[h] * sw2[(r * 64 + h) * 32 + t];
        float sg = 1.f / (1.f + expf(-a));
        sf_s[t] = sg * roi_s[t];
    }
    __syncthreads();
    {
        float a = pb1[r * 256 + t];
        for (int c = 0; c < 32; ++c) a += sf_s[c] * pw1[(r * 32 + c) * 256 + t];
        h2_s[t] = fmaxf(a, 0.f);
    }
    __syncthreads();
    {
        const int e = t & 127, hh = t >> 7;
        float a = 0.f;
        for (int h = hh * 128; h < hh * 128 + 128; ++h)
            a += h2_s[h] * pw2[(r * 256 + h) * 128 + e];
        if (hh) part[e] = a;
        __syncthreads();
        if (t < 128) outp[(b * 100 + r) * 128 + t] = part[t] + a + pb2[r * 128 + t];
    }
}

extern "C" void kernel_launch(void* const* d_in, const int* in_sizes, int n_in,
                              void* d_out, int out_size, void* d_ws, size_t ws_size,
                              hipStream_t stream) {
    const float* data = (const float*)d_in[0];
    const float* mask = (const float*)d_in[1];
    const float* w0   = (const float*)d_in[2];
    const float* wk   = (const float*)d_in[4];
    const float* sw1  = (const float*)d_in[6];
    const float* sb1  = (const float*)d_in[7];
    const float* sw2  = (const float*)d_in[8];
    const float* sb2  = (const float*)d_in[9];
    const float* pw1  = (const float*)d_in[10];
    const float* pb1  = (const float*)d_in[11];
    const float* pw2  = (const float*)d_in[12];
    const float* pb2  = (const float*)d_in[13];
    float* out = (float*)d_out;

    char* ws = (char*)d_ws;
    size_t off = 0;
    auto alloc = [&](size_t bytes) {
        void* p = ws + off;
        off += (bytes + 255) & ~(size_t)255;
        return p;
    };
    uint16_t* buf0 = (uint16_t*)alloc((size_t)2 * VV * 32 * 2);
    uint16_t* buf1 = (uint16_t*)alloc((size_t)2 * VV * 32 * 2);
    float* wT0     = (float*)alloc(27 * 32 * 4);
    float* wTk     = (float*)alloc((size_t)3 * 27 * 32 * 32 * 4);
    float2* spart  = (float2*)alloc((size_t)9216 * 2 * 32 * 8);
    float2* mr     = (float2*)alloc(4 * 64 * 8);
    float* rzone   = (float*)alloc((size_t)864 * 100 * 64 * 4);
    float* mzone   = (float*)alloc((size_t)864 * 100 * 4);
    float* roi     = (float*)alloc(2 * 100 * 32 * 4);
    (void)ws_size; (void)in_sizes; (void)n_in; (void)out_size;

    k_transpose_w<<<328, 256, 0, stream>>>(w0, wk, wT0, wTk);

    dim3 cgrid(96, 96, 2);
    k_conv0<<<cgrid, 256, 0, stream>>>(data, wT0, buf0, spart);
    k_finalize<<<64, 256, 0, stream>>>((const float2*)spart, mr + 0);

    k_convk<0><<<cgrid, 256, 0, stream>>>(buf0, mr + 0,   wTk + 0 * 27 * 32 * 32, buf1, spart);
    k_finalize<<<64, 256, 0, stream>>>((const float2*)spart, mr + 64);

    k_convk<0><<<cgrid, 256, 0, stream>>>(buf1, mr + 64,  wTk + 1 * 27 * 32 * 32, buf0, spart);
    k_finalize<<<64, 256, 0, stream>>>((const float2*)spart, mr + 128);

    k_convk<1><<<cgrid, 256, 0, stream>>>(buf0, mr + 128, wTk + 2 * 27 * 32 * 32, buf1, spart);
    k_finalize<<<64, 256, 0, stream>>>((const float2*)spart, mr + 192);

    k_prepass<<<dim3(432, 64), 256, 0, stream>>>(buf1, mr + 192);

    k_pool<<<864, 256, 0, stream>>>(buf1, mask, rzone, mzone);
    k_roifin<<<100, 256, 0, stream>>>(rzone, mzone, roi);

    k_mlp<<<dim3(100, 2), 256, 0, stream>>>(roi, sw1, sb1, sw2, sb2,
                                            pw1, pb1, pw2, pb2, out);
}

// Round 2
// 2079.167 us; speedup vs baseline: 5.4398x; 5.4398x over previous
//
#include <hip/hip_runtime.h>
#include <stdint.h>

#define DD 96
#define VV (96*96*96)   // 884736
#define EPSN 1e-5f

typedef short short8 __attribute__((ext_vector_type(8)));
typedef float floatx4 __attribute__((ext_vector_type(4)));

__device__ __forceinline__ float bf2f(uint32_t u_lo16) {
    union { uint32_t i; float f; } x; x.i = u_lo16 << 16; return x.f;
}
__device__ __forceinline__ uint16_t f2bf(float f) {
    union { float f; uint32_t i; } x; x.f = f;
    uint32_t r = x.i + 0x7FFFu + ((x.i >> 16) & 1u);
    return (uint16_t)(r >> 16);
}

// ---------------- weight packing ----------------
// wT0 [k][co] fp32 for conv0 (unchanged).
// wpk: per layer li, per tap, per n-tile nt, per lane l, 8 bf16:
//   wpk[((li*27+tap)*2+nt)*512 + l*8 + e] = wk[li][co=nt*16+(l&15)][ci=(l>>4)*8+e][tap]
__global__ void k_packw(const float* __restrict__ w0, const float* __restrict__ wk,
                        float* __restrict__ wT0, uint16_t* __restrict__ wpk) {
    int i = blockIdx.x * 256 + threadIdx.x;
    if (i < 27 * 32) {
        int co = i / 27, k = i % 27;
        wT0[k * 32 + co] = w0[i];
    }
    int j = i - 27 * 32;
    if (j >= 0 && j < 3 * 27 * 2 * 512) {
        int e = j & 7, l = (j >> 3) & 63, nt = (j >> 9) & 1;
        int r = j >> 10;              // li*27 + tap
        int tap = r % 27, li = r / 27;
        int co = nt * 16 + (l & 15), ci = (l >> 4) * 8 + e;
        float v = wk[((li * 32 + co) * 32 + ci) * 27 + tap];
        wpk[j] = f2bf(v);
    }
}

// ---------------- conv0: data fp32 [b][v] -> buf raw bf16 chan-last [b][v][c] + stat partials ----------
__global__ __launch_bounds__(256) void k_conv0(const float* __restrict__ data,
        const float* __restrict__ wT0, uint16_t* __restrict__ out,
        float2* __restrict__ spart) {
    const int y = blockIdx.x, z = blockIdx.y, b = blockIdx.z;
    const int t = threadIdx.x, co = t & 31, xs = t >> 5;
    const int xbase = xs * 12;
    __shared__ float in_s[98];
    __shared__ float wpart[4][32][2];

    float w0r[27];
#pragma unroll
    for (int k = 0; k < 27; ++k) w0r[k] = wT0[k * 32 + co];

    float acc[12];
#pragma unroll
    for (int j = 0; j < 12; ++j) acc[j] = 0.f;

    for (int row = 0; row < 9; ++row) {
        int dz = row / 3 - 1, dy = row % 3 - 1;
        int vz = z + dz, vy = y + dy;
        bool rowok = (vz >= 0 && vz < DD && vy >= 0 && vy < DD);
        long long rbase = (long long)b * VV + (long long)(vz * 96 + vy) * 96;
        __syncthreads();
        if (t < 98) {
            float v = 0.f;
            if (rowok && t >= 1 && t <= 96) v = data[rbase + (t - 1)];
            in_s[t] = v;
        }
        __syncthreads();
#pragma unroll
        for (int p = 0; p < 14; ++p) {
            float v = in_s[xbase + p];
#pragma unroll
            for (int dxi = 0; dxi < 3; ++dxi) {
                int j = p - dxi;
                if (j >= 0 && j < 12) acc[j] += v * w0r[row * 3 + dxi];
            }
        }
    }
    float s1 = 0.f, s2 = 0.f;
#pragma unroll
    for (int j = 0; j < 12; ++j) { s1 += acc[j]; s2 += acc[j] * acc[j]; }
    s1 += __shfl_xor(s1, 32, 64);
    s2 += __shfl_xor(s2, 32, 64);
    int wv = t >> 6;
    if ((t & 63) < 32) { wpart[wv][co][0] = s1; wpart[wv][co][1] = s2; }
    __syncthreads();
    if (t < 32) {
        float a = 0.f, c2 = 0.f;
#pragma unroll
        for (int w = 0; w < 4; ++w) { a += wpart[w][t][0]; c2 += wpart[w][t][1]; }
        int zone = z * 96 + y;
        spart[(zone * 2 + b) * 32 + t] = make_float2(a, c2);
    }
    long long obase = ((long long)b * VV + (long long)(z * 96 + y) * 96 + xbase) * 32 + co;
#pragma unroll
    for (int j = 0; j < 12; ++j) out[obase + (long long)j * 32] = f2bf(acc[j]);
}

// ---------------- stats finalize ----------------
__global__ void k_finalize(const float2* __restrict__ spart, float2* __restrict__ mr) {
    const int bc = blockIdx.x, t = threadIdx.x;
    float a = 0.f, s2 = 0.f;
    for (int z = t; z < 9216; z += 256) {
        float2 v = spart[z * 64 + bc];
        a += v.x; s2 += v.y;
    }
#pragma unroll
    for (int m = 1; m < 64; m <<= 1) {
        a  += __shfl_xor(a, m, 64);
        s2 += __shfl_xor(s2, m, 64);
    }
    __shared__ float2 wred[4];
    if ((t & 63) == 0) wred[t >> 6] = make_float2(a, s2);
    __syncthreads();
    if (t == 0) {
        float A = wred[0].x + wred[1].x + wred[2].x + wred[3].x;
        float S = wred[0].y + wred[1].y + wred[2].y + wred[3].y;
        float mean = A / (float)VV;
        float var = S / (float)VV - mean * mean;
        float rs = rsqrtf(fmaxf(var, 0.f) + EPSN);
        mr[bc] = make_float2(mean, rs);
    }
}

// ---------------- chan-last in-place normalize+relu: raw bf16 [b][v][c] -> normalized bf16 ------------
__global__ __launch_bounds__(256) void k_prepass_cl(uint16_t* __restrict__ emb,
                                                    const float2* __restrict__ mr) {
    __shared__ float2 mrs[64];
    if (threadIdx.x < 64) mrs[threadIdx.x] = mr[threadIdx.x];
    __syncthreads();
    const long long nchunk = (long long)2 * VV * 4;   // 8 u16 per chunk
    for (long long i = (long long)blockIdx.x * 256 + threadIdx.x; i < nchunk;
         i += (long long)gridDim.x * 256) {
        int g = (int)(i & 3);
        int b = (i >= (long long)VV * 4) ? 1 : 0;
        uint4* p = (uint4*)(emb) + i;
        uint4 raw = *p;
        uint32_t u[4] = {raw.x, raw.y, raw.z, raw.w};
        uint32_t o[4];
#pragma unroll
        for (int e = 0; e < 4; ++e) {
            int c = g * 8 + 2 * e;
            float2 m0 = mrs[b * 32 + c];
            float2 m1 = mrs[b * 32 + c + 1];
            float lo = bf2f(u[e] & 0xFFFFu);
            union { uint32_t i; float f; } hi; hi.i = u[e] & 0xFFFF0000u;
            float a0 = fmaxf(0.f, (lo   - m0.x) * m0.y);
            float a1 = fmaxf(0.f, (hi.f - m1.x) * m1.y);
            o[e] = (uint32_t)f2bf(a0) | ((uint32_t)f2bf(a1) << 16);
        }
        *p = make_uint4(o[0], o[1], o[2], o[3]);
    }
}

// ---------------- MFMA convk: normalized chan-last bf16 in -> raw bf16 out + stat partials ------------
// block = 512 threads = 8 waves, each wave = one (b,z,y) output row of 96 vox x 32 co.
template<int CHFIRST>
__global__ __launch_bounds__(512) void k_convk_mfma(const uint16_t* __restrict__ in,
        const uint16_t* __restrict__ wpk, uint16_t* __restrict__ out,
        float2* __restrict__ spart) {
    __shared__ uint16_t wlds[27 * 2 * 512];
    const int t = threadIdx.x;
    for (int i = t; i < 27 * 2 * 512 / 8; i += 512)
        ((short8*)wlds)[i] = ((const short8*)wpk)[i];
    __syncthreads();

    int bid = (int)blockIdx.x;
    bid = (bid & 7) * 288 + (bid >> 3);   // XCD swizzle (2304 % 8 == 0)
    const int yg = bid % 12; int tmp = bid / 12;
    const int z = tmp % 96; const int b = tmp / 96;
    const int w = t >> 6, lane = t & 63;
    const int y = yg * 8 + w;
    const int vx = lane & 15, kg = lane >> 4;

    floatx4 acc[6][2];
#pragma unroll
    for (int mt = 0; mt < 6; ++mt) {
        acc[mt][0] = (floatx4){0.f, 0.f, 0.f, 0.f};
        acc[mt][1] = (floatx4){0.f, 0.f, 0.f, 0.f};
    }

    const uint16_t* inb = in + (long long)b * VV * 32;

#pragma unroll 1
    for (int dz = 0; dz < 3; ++dz) {
        int vz = z + dz - 1;
        if ((unsigned)vz >= 96u) continue;
#pragma unroll 1
        for (int dy = 0; dy < 3; ++dy) {
            int vy = y + dy - 1;
            if ((unsigned)vy >= 96u) continue;
            const uint16_t* rowp = inb + (long long)(vz * 96 + vy) * 96 * 32;
            const int tap0 = (dz * 3 + dy) * 3;
#pragma unroll
            for (int dx = 0; dx < 3; ++dx) {
                const int toff = (tap0 + dx) * 1024;
                const short8 wb0 = *(const short8*)&wlds[toff + lane * 8];
                const short8 wb1 = *(const short8*)&wlds[toff + 512 + lane * 8];
#pragma unroll
                for (int mt = 0; mt < 6; ++mt) {
                    int x = mt * 16 + vx + dx - 1;
                    short8 a;
                    if ((mt == 0 && dx == 0) || (mt == 5 && dx == 2)) {
                        int xc = min(max(x, 0), 95);
                        a = *(const short8*)&rowp[xc * 32 + kg * 8];
                        if (x != xc) {
                            short8 zz = {0, 0, 0, 0, 0, 0, 0, 0};
                            a = zz;
                        }
                    } else {
                        a = *(const short8*)&rowp[x * 32 + kg * 8];
                    }
                    acc[mt][0] = __builtin_amdgcn_mfma_f32_16x16x32_bf16(a, wb0, acc[mt][0], 0, 0, 0);
                    acc[mt][1] = __builtin_amdgcn_mfma_f32_16x16x32_bf16(a, wb1, acc[mt][1], 0, 0, 0);
                }
            }
        }
    }

    // stats on raw outputs: lane covers co = vx (n0) and vx+16 (n1), rows kg*4+j per mt
    float s1n0 = 0.f, s2n0 = 0.f, s1n1 = 0.f, s2n1 = 0.f;
#pragma unroll
    for (int mt = 0; mt < 6; ++mt)
#pragma unroll
        for (int j = 0; j < 4; ++j) {
            float v0 = acc[mt][0][j], v1 = acc[mt][1][j];
            s1n0 += v0; s2n0 += v0 * v0;
            s1n1 += v1; s2n1 += v1 * v1;
        }
    s1n0 += __shfl_xor(s1n0, 16, 64); s1n0 += __shfl_xor(s1n0, 32, 64);
    s2n0 += __shfl_xor(s2n0, 16, 64); s2n0 += __shfl_xor(s2n0, 32, 64);
    s1n1 += __shfl_xor(s1n1, 16, 64); s1n1 += __shfl_xor(s1n1, 32, 64);
    s2n1 += __shfl_xor(s2n1, 16, 64); s2n1 += __shfl_xor(s2n1, 32, 64);
    if (lane < 16) {
        int zone = z * 96 + y;
        spart[(zone * 2 + b) * 32 + lane]      = make_float2(s1n0, s2n0);
        spart[(zone * 2 + b) * 32 + lane + 16] = make_float2(s1n1, s2n1);
    }

    if (CHFIRST) {
        // chan-first raw: out[(b*32+co)*VV + vox]; pack 4 consecutive vox (j=0..3) into 8B
        long long vbase = (long long)(z * 96 + y) * 96;
#pragma unroll
        for (int mt = 0; mt < 6; ++mt)
#pragma unroll
            for (int nt = 0; nt < 2; ++nt) {
                uint32_t lo = (uint32_t)f2bf(acc[mt][nt][0]) | ((uint32_t)f2bf(acc[mt][nt][1]) << 16);
                uint32_t hi = (uint32_t)f2bf(acc[mt][nt][2]) | ((uint32_t)f2bf(acc[mt][nt][3]) << 16);
                long long co = b * 32 + nt * 16 + vx;
                uint2* dst = (uint2*)&out[co * VV + vbase + mt * 16 + kg * 4];
                *dst = make_uint2(lo, hi);
            }
    } else {
        // chan-last raw: out[(b*VV + vox)*32 + co]
        long long obase = ((long long)b * VV + (long long)(z * 96 + y) * 96) * 32;
#pragma unroll
        for (int mt = 0; mt < 6; ++mt)
#pragma unroll
            for (int nt = 0; nt < 2; ++nt)
#pragma unroll
                for (int j = 0; j < 4; ++j)
                    out[obase + (long long)(mt * 16 + kg * 4 + j) * 32 + nt * 16 + vx] =
                        f2bf(acc[mt][nt][j]);
    }
}

// ---------------- chan-first in-place normalize (final layer, feeds pool) ----------------
__global__ __launch_bounds__(256) void k_prepass(uint16_t* __restrict__ emb,
                                                 const float2* __restrict__ mr) {
    const int bc = blockIdx.y;
    float2 v = mr[bc];
    const float m = v.x, rs = v.y;
    long long idx = (long long)bc * VV + ((long long)blockIdx.x * 256 + threadIdx.x) * 8;
    uint4* p = (uint4*)(emb + idx);
    uint4 raw = *p;
    uint32_t u[4] = {raw.x, raw.y, raw.z, raw.w};
    uint32_t o[4];
#pragma unroll
    for (int e = 0; e < 4; ++e) {
        float lo = bf2f(u[e] & 0xFFFFu);
        union { uint32_t i; float f; } hi; hi.i = u[e] & 0xFFFF0000u;
        float a = fmaxf(0.f, (lo   - m) * rs);
        float b = fmaxf(0.f, (hi.f - m) * rs);
        o[e] = (uint32_t)f2bf(a) | ((uint32_t)f2bf(b) << 16);
    }
    *p = make_uint4(o[0], o[1], o[2], o[3]);
}

// ---------------- pooling: emb bf16 chan-first [bc][v] x mask fp32 [r][v] -> zone partials ------------
__global__ __launch_bounds__(256) void k_pool(const uint16_t* __restrict__ emb,
        const float* __restrict__ mask, float* __restrict__ rzone,
        float* __restrict__ mzone) {
    const int t = threadIdx.x;
    const int bcg = t & 15, rg = t >> 4;
    const int bc0 = bcg * 4, r0 = rg * 4;
    const long long cb = (long long)blockIdx.x * 1024;

    float acc[2][4][4];
#pragma unroll
    for (int rb = 0; rb < 2; ++rb)
#pragma unroll
        for (int ri = 0; ri < 4; ++ri)
#pragma unroll
            for (int bi = 0; bi < 4; ++bi) acc[rb][ri][bi] = 0.f;
    float macc[2][4] = {{0.f, 0.f, 0.f, 0.f}, {0.f, 0.f, 0.f, 0.f}};

    for (int it = 0; it < 128; ++it) {
        long long v0 = cb + it * 8;
        float ef[4][8];
#pragma unroll
        for (int bi = 0; bi < 4; ++bi) {
            uint4 raw = *(const uint4*)(emb + (long long)(bc0 + bi) * VV + v0);
            uint32_t u[4] = {raw.x, raw.y, raw.z, raw.w};
#pragma unroll
            for (int e = 0; e < 4; ++e) {
                ef[bi][2 * e] = bf2f(u[e] & 0xFFFFu);
                union { uint32_t i; float f; } hi; hi.i = u[e] & 0xFFFF0000u;
                ef[bi][2 * e + 1] = hi.f;
            }
        }
#pragma unroll
        for (int rb = 0; rb < 2; ++rb) {
#pragma unroll
            for (int ri = 0; ri < 4; ++ri) {
                int r = r0 + rb * 64 + ri;
                float4 m0, m1;
                if (r < 100) {
                    const float* mp = mask + (long long)r * VV + v0;
                    m0 = *(const float4*)mp;
                    m1 = *(const float4*)(mp + 4);
                } else {
                    m0 = make_float4(0.f, 0.f, 0.f, 0.f);
                    m1 = m0;
                }
                if (bcg == 0)
                    macc[rb][ri] += m0.x + m0.y + m0.z + m0.w + m1.x + m1.y + m1.z + m1.w;
#pragma unroll
                for (int bi = 0; bi < 4; ++bi) {
                    acc[rb][ri][bi] += ef[bi][0] * m0.x + ef[bi][1] * m0.y
                                     + ef[bi][2] * m0.z + ef[bi][3] * m0.w
                                     + ef[bi][4] * m1.x + ef[bi][5] * m1.y
                                     + ef[bi][6] * m1.z + ef[bi][7] * m1.w;
                }
            }
        }
    }
#pragma unroll
    for (int rb = 0; rb < 2; ++rb)
#pragma unroll
        for (int ri = 0; ri < 4; ++ri) {
            int r = r0 + rb * 64 + ri;
            if (r < 100) {
#pragma unroll
                for (int bi = 0; bi < 4; ++bi)
                    rzone[((long long)blockIdx.x * 100 + r) * 64 + bc0 + bi] = acc[rb][ri][bi];
                if (bcg == 0) mzone[blockIdx.x * 100 + r] = macc[rb][ri];
            }
        }
}

// ---------------- roi finalize ----------------
__global__ void k_roifin(const float* __restrict__ rzone, const float* __restrict__ mzone,
                         float* __restrict__ roi) {
    const int r = blockIdx.x, t = threadIdx.x;
    __shared__ float sred[256];
    float ms = 0.f;
    for (int z = t; z < 864; z += 256) ms += mzone[z * 100 + r];
    sred[t] = ms;
    __syncthreads();
    for (int s = 128; s > 0; s >>= 1) {
        if (t < s) sred[t] += sred[t + s];
        __syncthreads();
    }
    float msum = sred[0];
    const int bc = t & 63, zs = t >> 6;
    float a = 0.f;
    for (int z = zs; z < 864; z += 4) a += rzone[((long long)z * 100 + r) * 64 + bc];
    __shared__ float s2[4][64];
    s2[zs][bc] = a;
    __syncthreads();
    if (t < 64) {
        float v = s2[0][t] + s2[1][t] + s2[2][t] + s2[3][t];
        int b = t >> 5, c = t & 31;
        roi[(b * 100 + r) * 32 + c] = v / msum;
    }
}

// ---------------- per-ROI MLPs ----------------
__global__ __launch_bounds__(256) void k_mlp(const float* __restrict__ roi,
        const float* __restrict__ sw1, const float* __restrict__ sb1,
        const float* __restrict__ sw2, const float* __restrict__ sb2,
        const float* __restrict__ pw1, const float* __restrict__ pb1,
        const float* __restrict__ pw2, const float* __restrict__ pb2,
        float* __restrict__ outp) {
    const int r = blockIdx.x, b = blockIdx.y, t = threadIdx.x;
    __shared__ float roi_s[32], h1_s[64], sf_s[32], h2_s[256], part[128];
    if (t < 32) roi_s[t] = roi[(b * 100 + r) * 32 + t];
    __syncthreads();
    if (t < 64) {
        float a = sb1[r * 64 + t];
        for (int c = 0; c < 32; ++c) a += roi_s[c] * sw1[(r * 32 + c) * 64 + t];
        h1_s[t] = fmaxf(a, 0.f);
    }
    __syncthreads();
    if (t < 32) {
        float a = sb2[r * 32 + t];
        for (int h = 0; h < 64; ++h) a += h1_s[h] * sw2[(r * 64 + h) * 32 + t];
        float sg = 1.f / (1.f + expf(-a));
        sf_s[t] = sg * roi_s[t];
    }
    __syncthreads();
    {
        float a = pb1[r * 256 + t];
        for (int c = 0; c < 32; ++c) a += sf_s[c] * pw1[(r * 32 + c) * 256 + t];
        h2_s[t] = fmaxf(a, 0.f);
    }
    __syncthreads();
    {
        const int e = t & 127, hh = t >> 7;
        float a = 0.f;
        for (int h = hh * 128; h < hh * 128 + 128; ++h)
            a += h2_s[h] * pw2[(r * 256 + h) * 128 + e];
        if (hh) part[e] = a;
        __syncthreads();
        if (t < 128) outp[(b * 100 + r) * 128 + t] = part[t] + a + pb2[r * 128 + t];
    }
}

extern "C" void kernel_launch(void* const* d_in, const int* in_sizes, int n_in,
                              void* d_out, int out_size, void* d_ws, size_t ws_size,
                              hipStream_t stream) {
    const float* data = (const float*)d_in[0];
    const float* mask = (const float*)d_in[1];
    const float* w0   = (const float*)d_in[2];
    const float* wk   = (const float*)d_in[4];
    const float* sw1  = (const float*)d_in[6];
    const float* sb1  = (const float*)d_in[7];
    const float* sw2  = (const float*)d_in[8];
    const float* sb2  = (const float*)d_in[9];
    const float* pw1  = (const float*)d_in[10];
    const float* pb1  = (const float*)d_in[11];
    const float* pw2  = (const float*)d_in[12];
    const float* pb2  = (const float*)d_in[13];
    float* out = (float*)d_out;

    char* ws = (char*)d_ws;
    size_t off = 0;
    auto alloc = [&](size_t bytes) {
        void* p = ws + off;
        off += (bytes + 255) & ~(size_t)255;
        return p;
    };
    uint16_t* buf0 = (uint16_t*)alloc((size_t)2 * VV * 32 * 2);
    uint16_t* buf1 = (uint16_t*)alloc((size_t)2 * VV * 32 * 2);
    float* wT0     = (float*)alloc(27 * 32 * 4);
    uint16_t* wpk  = (uint16_t*)alloc((size_t)3 * 27 * 2 * 512 * 2);
    float2* spart  = (float2*)alloc((size_t)9216 * 2 * 32 * 8);
    float2* mr     = (float2*)alloc(4 * 64 * 8);
    float* rzone   = (float*)alloc((size_t)864 * 100 * 64 * 4);
    float* mzone   = (float*)alloc((size_t)864 * 100 * 4);
    float* roi     = (float*)alloc(2 * 100 * 32 * 4);
    (void)ws_size; (void)in_sizes; (void)n_in; (void)out_size;

    k_packw<<<328, 256, 0, stream>>>(w0, wk, wT0, wpk);

    dim3 cgrid(96, 96, 2);
    k_conv0<<<cgrid, 256, 0, stream>>>(data, wT0, buf0, spart);
    k_finalize<<<64, 256, 0, stream>>>((const float2*)spart, mr + 0);
    k_prepass_cl<<<2048, 256, 0, stream>>>(buf0, mr + 0);

    k_convk_mfma<0><<<2304, 512, 0, stream>>>(buf0, wpk + 0 * 27648, buf1, spart);
    k_finalize<<<64, 256, 0, stream>>>((const float2*)spart, mr + 64);
    k_prepass_cl<<<2048, 256, 0, stream>>>(buf1, mr + 64);

    k_convk_mfma<0><<<2304, 512, 0, stream>>>(buf1, wpk + 1 * 27648, buf0, spart);
    k_finalize<<<64, 256, 0, stream>>>((const float2*)spart, mr + 128);
    k_prepass_cl<<<2048, 256, 0, stream>>>(buf0, mr + 128);

    k_convk_mfma<1><<<2304, 512, 0, stream>>>(buf0, wpk + 2 * 27648, buf1, spart);
    k_finalize<<<64, 256, 0, stream>>>((const float2*)spart, mr + 192);
    k_prepass<<<dim3(432, 64), 256, 0, stream>>>(buf1, mr + 192);

    k_pool<<<864, 256, 0, stream>>>(buf1, mask, rzone, mzone);
    k_roifin<<<100, 256, 0, stream>>>(rzone, mzone, roi);

    k_mlp<<<dim3(100, 2), 256, 0, stream>>>(roi, sw1, sb1, sw2, sb2,
                                            pw1, pb1, pw2, pb2, out);
}

// Round 3
// 1181.657 us; speedup vs baseline: 9.5716x; 1.7595x over previous
//
#include <hip/hip_runtime.h>
#include <stdint.h>

#define DD 96
#define VV (96*96*96)   // 884736
#define EPSN 1e-5f

typedef short short8 __attribute__((ext_vector_type(8)));
typedef float floatx4 __attribute__((ext_vector_type(4)));

__device__ __forceinline__ float bf2f(uint32_t u_lo16) {
    union { uint32_t i; float f; } x; x.i = u_lo16 << 16; return x.f;
}
__device__ __forceinline__ uint16_t f2bf(float f) {
    union { float f; uint32_t i; } x; x.f = f;
    uint32_t r = x.i + 0x7FFFu + ((x.i >> 16) & 1u);
    return (uint16_t)(r >> 16);
}
__device__ __forceinline__ uint32_t cvtpk(float lo, float hi) {
    uint32_t r;
    asm("v_cvt_pk_bf16_f32 %0, %1, %2" : "=v"(r) : "v"(lo), "v"(hi));
    return r;
}

// ---------------- weight packing ----------------
__global__ void k_packw(const float* __restrict__ w0, const float* __restrict__ wk,
                        float* __restrict__ wT0, uint16_t* __restrict__ wpk) {
    int i = blockIdx.x * 256 + threadIdx.x;
    if (i < 27 * 32) {
        int co = i / 27, k = i % 27;
        wT0[k * 32 + co] = w0[i];
    }
    int j = i - 27 * 32;
    if (j >= 0 && j < 3 * 27 * 2 * 512) {
        int e = j & 7, l = (j >> 3) & 63, nt = (j >> 9) & 1;
        int r = j >> 10;              // li*27 + tap
        int tap = r % 27, li = r / 27;
        int co = nt * 16 + (l & 15), ci = (l >> 4) * 8 + e;
        float v = wk[((li * 32 + co) * 32 + ci) * 27 + tap];
        wpk[j] = f2bf(v);
    }
}

// ---------------- conv0 ----------------
__global__ __launch_bounds__(256) void k_conv0(const float* __restrict__ data,
        const float* __restrict__ wT0, uint16_t* __restrict__ out,
        float2* __restrict__ spart) {
    const int y = blockIdx.x, z = blockIdx.y, b = blockIdx.z;
    const int t = threadIdx.x, co = t & 31, xs = t >> 5;
    const int xbase = xs * 12;
    __shared__ float in_s[98];
    __shared__ float wpart[4][32][2];

    float w0r[27];
#pragma unroll
    for (int k = 0; k < 27; ++k) w0r[k] = wT0[k * 32 + co];

    float acc[12];
#pragma unroll
    for (int j = 0; j < 12; ++j) acc[j] = 0.f;

    for (int row = 0; row < 9; ++row) {
        int dz = row / 3 - 1, dy = row % 3 - 1;
        int vz = z + dz, vy = y + dy;
        bool rowok = (vz >= 0 && vz < DD && vy >= 0 && vy < DD);
        long long rbase = (long long)b * VV + (long long)(vz * 96 + vy) * 96;
        __syncthreads();
        if (t < 98) {
            float v = 0.f;
            if (rowok && t >= 1 && t <= 96) v = data[rbase + (t - 1)];
            in_s[t] = v;
        }
        __syncthreads();
#pragma unroll
        for (int p = 0; p < 14; ++p) {
            float v = in_s[xbase + p];
#pragma unroll
            for (int dxi = 0; dxi < 3; ++dxi) {
                int j = p - dxi;
                if (j >= 0 && j < 12) acc[j] += v * w0r[row * 3 + dxi];
            }
        }
    }
    float s1 = 0.f, s2 = 0.f;
#pragma unroll
    for (int j = 0; j < 12; ++j) { s1 += acc[j]; s2 += acc[j] * acc[j]; }
    s1 += __shfl_xor(s1, 32, 64);
    s2 += __shfl_xor(s2, 32, 64);
    int wv = t >> 6;
    if ((t & 63) < 32) { wpart[wv][co][0] = s1; wpart[wv][co][1] = s2; }
    __syncthreads();
    if (t < 32) {
        float a = 0.f, c2 = 0.f;
#pragma unroll
        for (int w = 0; w < 4; ++w) { a += wpart[w][t][0]; c2 += wpart[w][t][1]; }
        int zone = z * 96 + y;
        spart[(zone * 2 + b) * 32 + t] = make_float2(a, c2);
    }
    long long obase = ((long long)b * VV + (long long)(z * 96 + y) * 96 + xbase) * 32 + co;
#pragma unroll
    for (int j = 0; j < 12; ++j) out[obase + (long long)j * 32] = f2bf(acc[j]);
}

// ---------------- stats finalize ----------------
__global__ void k_finalize(const float2* __restrict__ spart, float2* __restrict__ mr) {
    const int bc = blockIdx.x, t = threadIdx.x;
    float a = 0.f, s2 = 0.f;
    for (int z = t; z < 9216; z += 256) {
        float2 v = spart[z * 64 + bc];
        a += v.x; s2 += v.y;
    }
#pragma unroll
    for (int m = 1; m < 64; m <<= 1) {
        a  += __shfl_xor(a, m, 64);
        s2 += __shfl_xor(s2, m, 64);
    }
    __shared__ float2 wred[4];
    if ((t & 63) == 0) wred[t >> 6] = make_float2(a, s2);
    __syncthreads();
    if (t == 0) {
        float A = wred[0].x + wred[1].x + wred[2].x + wred[3].x;
        float S = wred[0].y + wred[1].y + wred[2].y + wred[3].y;
        float mean = A / (float)VV;
        float var = S / (float)VV - mean * mean;
        float rs = rsqrtf(fmaxf(var, 0.f) + EPSN);
        mr[bc] = make_float2(mean, rs);
    }
}

// ---------------- chan-last in-place normalize+relu ----------------
__global__ __launch_bounds__(256) void k_prepass_cl(uint16_t* __restrict__ emb,
                                                    const float2* __restrict__ mr) {
    __shared__ float2 mrs[64];
    if (threadIdx.x < 64) mrs[threadIdx.x] = mr[threadIdx.x];
    __syncthreads();
    const long long nchunk = (long long)2 * VV * 4;   // 8 u16 per chunk
    for (long long i = (long long)blockIdx.x * 256 + threadIdx.x; i < nchunk;
         i += (long long)gridDim.x * 256) {
        int g = (int)(i & 3);
        int b = (i >= (long long)VV * 4) ? 1 : 0;
        uint4* p = (uint4*)(emb) + i;
        uint4 raw = *p;
        uint32_t u[4] = {raw.x, raw.y, raw.z, raw.w};
        uint32_t o[4];
#pragma unroll
        for (int e = 0; e < 4; ++e) {
            int c = g * 8 + 2 * e;
            float2 m0 = mrs[b * 32 + c];
            float2 m1 = mrs[b * 32 + c + 1];
            float lo = bf2f(u[e] & 0xFFFFu);
            union { uint32_t i; float f; } hi; hi.i = u[e] & 0xFFFF0000u;
            float a0 = fmaxf(0.f, (lo   - m0.x) * m0.y);
            float a1 = fmaxf(0.f, (hi.f - m1.x) * m1.y);
            o[e] = (uint32_t)f2bf(a0) | ((uint32_t)f2bf(a1) << 16);
        }
        *p = make_uint4(o[0], o[1], o[2], o[3]);
    }
}

// ---------------- MFMA convk ----------------
template<int CHFIRST>
__global__ __launch_bounds__(512) void k_convk_mfma(const uint16_t* __restrict__ in,
        const uint16_t* __restrict__ wpk, uint16_t* __restrict__ out,
        float2* __restrict__ spart) {
    __shared__ uint16_t wlds[27 * 2 * 512];
    const int t = threadIdx.x;
    for (int i = t; i < 27 * 2 * 512 / 8; i += 512)
        ((short8*)wlds)[i] = ((const short8*)wpk)[i];
    __syncthreads();

    int bid = (int)blockIdx.x;
    bid = (bid & 7) * 288 + (bid >> 3);   // XCD swizzle (2304 % 8 == 0)
    const int yg = bid % 12; int tmp = bid / 12;
    const int z = tmp % 96; const int b = tmp / 96;
    const int w = t >> 6, lane = t & 63;
    const int y = yg * 8 + w;
    const int vx = lane & 15, kg = lane >> 4;

    floatx4 acc[6][2];
#pragma unroll
    for (int mt = 0; mt < 6; ++mt) {
        acc[mt][0] = (floatx4){0.f, 0.f, 0.f, 0.f};
        acc[mt][1] = (floatx4){0.f, 0.f, 0.f, 0.f};
    }

    const uint16_t* inb = in + (long long)b * VV * 32;

#pragma unroll 1
    for (int dz = 0; dz < 3; ++dz) {
        int vz = z + dz - 1;
        if ((unsigned)vz >= 96u) continue;
#pragma unroll 1
        for (int dy = 0; dy < 3; ++dy) {
            int vy = y + dy - 1;
            if ((unsigned)vy >= 96u) continue;
            const uint16_t* rowp = inb + (long long)(vz * 96 + vy) * 96 * 32;
            const int tap0 = (dz * 3 + dy) * 3;
#pragma unroll
            for (int dx = 0; dx < 3; ++dx) {
                const int toff = (tap0 + dx) * 1024;
                const short8 wb0 = *(const short8*)&wlds[toff + lane * 8];
                const short8 wb1 = *(const short8*)&wlds[toff + 512 + lane * 8];
#pragma unroll
                for (int mt = 0; mt < 6; ++mt) {
                    int x = mt * 16 + vx + dx - 1;
                    short8 a;
                    if ((mt == 0 && dx == 0) || (mt == 5 && dx == 2)) {
                        int xc = min(max(x, 0), 95);
                        a = *(const short8*)&rowp[xc * 32 + kg * 8];
                        if (x != xc) {
                            short8 zz = {0, 0, 0, 0, 0, 0, 0, 0};
                            a = zz;
                        }
                    } else {
                        a = *(const short8*)&rowp[x * 32 + kg * 8];
                    }
                    acc[mt][0] = __builtin_amdgcn_mfma_f32_16x16x32_bf16(a, wb0, acc[mt][0], 0, 0, 0);
                    acc[mt][1] = __builtin_amdgcn_mfma_f32_16x16x32_bf16(a, wb1, acc[mt][1], 0, 0, 0);
                }
            }
        }
    }

    float s1n0 = 0.f, s2n0 = 0.f, s1n1 = 0.f, s2n1 = 0.f;
#pragma unroll
    for (int mt = 0; mt < 6; ++mt)
#pragma unroll
        for (int j = 0; j < 4; ++j) {
            float v0 = acc[mt][0][j], v1 = acc[mt][1][j];
            s1n0 += v0; s2n0 += v0 * v0;
            s1n1 += v1; s2n1 += v1 * v1;
        }
    s1n0 += __shfl_xor(s1n0, 16, 64); s1n0 += __shfl_xor(s1n0, 32, 64);
    s2n0 += __shfl_xor(s2n0, 16, 64); s2n0 += __shfl_xor(s2n0, 32, 64);
    s1n1 += __shfl_xor(s1n1, 16, 64); s1n1 += __shfl_xor(s1n1, 32, 64);
    s2n1 += __shfl_xor(s2n1, 16, 64); s2n1 += __shfl_xor(s2n1, 32, 64);
    if (lane < 16) {
        int zone = z * 96 + y;
        spart[(zone * 2 + b) * 32 + lane]      = make_float2(s1n0, s2n0);
        spart[(zone * 2 + b) * 32 + lane + 16] = make_float2(s1n1, s2n1);
    }

    if (CHFIRST) {
        long long vbase = (long long)(z * 96 + y) * 96;
#pragma unroll
        for (int mt = 0; mt < 6; ++mt)
#pragma unroll
            for (int nt = 0; nt < 2; ++nt) {
                uint32_t lo = (uint32_t)f2bf(acc[mt][nt][0]) | ((uint32_t)f2bf(acc[mt][nt][1]) << 16);
                uint32_t hi = (uint32_t)f2bf(acc[mt][nt][2]) | ((uint32_t)f2bf(acc[mt][nt][3]) << 16);
                long long co = b * 32 + nt * 16 + vx;
                uint2* dst = (uint2*)&out[co * VV + vbase + mt * 16 + kg * 4];
                *dst = make_uint2(lo, hi);
            }
    } else {
        long long obase = ((long long)b * VV + (long long)(z * 96 + y) * 96) * 32;
#pragma unroll
        for (int mt = 0; mt < 6; ++mt)
#pragma unroll
            for (int nt = 0; nt < 2; ++nt)
#pragma unroll
                for (int j = 0; j < 4; ++j)
                    out[obase + (long long)(mt * 16 + kg * 4 + j) * 32 + nt * 16 + vx] =
                        f2bf(acc[mt][nt][j]);
    }
}

// ---------------- MFMA pooling with fused instance-norm+relu ----------------
// grid = 864 zones (1024 vox each); block = 448 thr = 7 waves.
// wave w = r-tile (16 rows, rows 96..111 clamped); each wave covers all 4 bc-tiles.
// A = mask rows (fp32 -> bf16 in-register), B = raw chan-first emb (normalize+relu in-register).
__global__ __launch_bounds__(448) void k_pool_mfma(const uint16_t* __restrict__ emb,
        const float* __restrict__ mask, const float2* __restrict__ mr,
        float* __restrict__ rzone, float* __restrict__ mzone) {
    const int t = threadIdx.x;
    const int rt = t >> 6, lane = t & 63;
    const int rl = lane & 15, kq = lane >> 4;
    const int r = rt * 16 + rl;
    const int rc = min(r, 99);
    const long long v0 = (long long)blockIdx.x * 1024;

    // per-lane normalization constants: this lane's bc column per bc-tile
    float nA[4], nB[4];
#pragma unroll
    for (int bct = 0; bct < 4; ++bct) {
        float2 v = mr[bct * 16 + rl];
        nA[bct] = v.y;              // rs
        nB[bct] = -v.x * v.y;       // -m*rs
    }

    floatx4 acc[4];
#pragma unroll
    for (int bct = 0; bct < 4; ++bct) acc[bct] = (floatx4){0.f, 0.f, 0.f, 0.f};
    float msum = 0.f;

    const float* mrow = mask + (long long)rc * VV + v0 + kq * 8;
    const uint16_t* eb0 = emb + (long long)(0 * 16 + rl) * VV + v0 + kq * 8;
    const uint16_t* eb1 = emb + (long long)(1 * 16 + rl) * VV + v0 + kq * 8;
    const uint16_t* eb2 = emb + (long long)(2 * 16 + rl) * VV + v0 + kq * 8;
    const uint16_t* eb3 = emb + (long long)(3 * 16 + rl) * VV + v0 + kq * 8;
    const uint16_t* ebase[4] = {eb0, eb1, eb2, eb3};

#pragma unroll 2
    for (int ks = 0; ks < 32; ++ks) {
        const float4 a0 = *(const float4*)(mrow + ks * 32);
        const float4 a1 = *(const float4*)(mrow + ks * 32 + 4);
        msum += (a0.x + a0.y + a0.z + a0.w) + (a1.x + a1.y + a1.z + a1.w);
        union { uint32_t u[4]; short8 s; } af;
        af.u[0] = cvtpk(a0.x, a0.y);
        af.u[1] = cvtpk(a0.z, a0.w);
        af.u[2] = cvtpk(a1.x, a1.y);
        af.u[3] = cvtpk(a1.z, a1.w);
#pragma unroll
        for (int bct = 0; bct < 4; ++bct) {
            uint4 raw = *(const uint4*)(ebase[bct] + ks * 32);
            uint32_t u[4] = {raw.x, raw.y, raw.z, raw.w};
            union { uint32_t u[4]; short8 s; } bfr;
#pragma unroll
            for (int e = 0; e < 4; ++e) {
                float lo = bf2f(u[e] & 0xFFFFu);
                union { uint32_t i; float f; } hv; hv.i = u[e] & 0xFFFF0000u;
                float x0 = fmaxf(0.f, fmaf(lo,   nA[bct], nB[bct]));
                float x1 = fmaxf(0.f, fmaf(hv.f, nA[bct], nB[bct]));
                bfr.u[e] = cvtpk(x0, x1);
            }
            acc[bct] = __builtin_amdgcn_mfma_f32_16x16x32_bf16(af.s, bfr.s, acc[bct], 0, 0, 0);
        }
    }

    // mask row sums: reduce over the 4 k-quarters
    msum += __shfl_xor(msum, 16, 64);
    msum += __shfl_xor(msum, 32, 64);
    if (lane < 16 && r < 100)
        mzone[blockIdx.x * 100 + r] = msum;

    // store C: row = rt*16 + kq*4 + reg, col = bct*16 + rl
#pragma unroll
    for (int bct = 0; bct < 4; ++bct)
#pragma unroll
        for (int reg = 0; reg < 4; ++reg) {
            int rr = rt * 16 + kq * 4 + reg;
            if (rr < 100)
                rzone[((long long)blockIdx.x * 100 + rr) * 64 + bct * 16 + rl] = acc[bct][reg];
        }
}

// ---------------- roi finalize ----------------
__global__ void k_roifin(const float* __restrict__ rzone, const float* __restrict__ mzone,
                         float* __restrict__ roi) {
    const int r = blockIdx.x, t = threadIdx.x;
    __shared__ float sred[256];
    float ms = 0.f;
    for (int z = t; z < 864; z += 256) ms += mzone[z * 100 + r];
    sred[t] = ms;
    __syncthreads();
    for (int s = 128; s > 0; s >>= 1) {
        if (t < s) sred[t] += sred[t + s];
        __syncthreads();
    }
    float msum = sred[0];
    const int bc = t & 63, zs = t >> 6;
    float a = 0.f;
    for (int z = zs; z < 864; z += 4) a += rzone[((long long)z * 100 + r) * 64 + bc];
    __shared__ float s2[4][64];
    s2[zs][bc] = a;
    __syncthreads();
    if (t < 64) {
        float v = s2[0][t] + s2[1][t] + s2[2][t] + s2[3][t];
        int b = t >> 5, c = t & 31;
        roi[(b * 100 + r) * 32 + c] = v / msum;
    }
}

// ---------------- per-ROI MLPs ----------------
__global__ __launch_bounds__(256) void k_mlp(const float* __restrict__ roi,
        const float* __restrict__ sw1, const float* __restrict__ sb1,
        const float* __restrict__ sw2, const float* __restrict__ sb2,
        const float* __restrict__ pw1, const float* __restrict__ pb1,
        const float* __restrict__ pw2, const float* __restrict__ pb2,
        float* __restrict__ outp) {
    const int r = blockIdx.x, b = blockIdx.y, t = threadIdx.x;
    __shared__ float roi_s[32], h1_s[64], sf_s[32], h2_s[256], part[128];
    if (t < 32) roi_s[t] = roi[(b * 100 + r) * 32 + t];
    __syncthreads();
    if (t < 64) {
        float a = sb1[r * 64 + t];
        for (int c = 0; c < 32; ++c) a += roi_s[c] * sw1[(r * 32 + c) * 64 + t];
        h1_s[t] = fmaxf(a, 0.f);
    }
    __syncthreads();
    if (t < 32) {
        float a = sb2[r * 32 + t];
        for (int h = 0; h < 64; ++h) a += h1_s[h] * sw2[(r * 64 + h) * 32 + t];
        float sg = 1.f / (1.f + expf(-a));
        sf_s[t] = sg * roi_s[t];
    }
    __syncthreads();
    {
        float a = pb1[r * 256 + t];
        for (int c = 0; c < 32; ++c) a += sf_s[c] * pw1[(r * 32 + c) * 256 + t];
        h2_s[t] = fmaxf(a, 0.f);
    }
    __syncthreads();
    {
        const int e = t & 127, hh = t >> 7;
        float a = 0.f;
        for (int h = hh * 128; h < hh * 128 + 128; ++h)
            a += h2_s[h] * pw2[(r * 256 + h) * 128 + e];
        if (hh) part[e] = a;
        __syncthreads();
        if (t < 128) outp[(b * 100 + r) * 128 + t] = part[t] + a + pb2[r * 128 + t];
    }
}

extern "C" void kernel_launch(void* const* d_in, const int* in_sizes, int n_in,
                              void* d_out, int out_size, void* d_ws, size_t ws_size,
                              hipStream_t stream) {
    const float* data = (const float*)d_in[0];
    const float* mask = (const float*)d_in[1];
    const float* w0   = (const float*)d_in[2];
    const float* wk   = (const float*)d_in[4];
    const float* sw1  = (const float*)d_in[6];
    const float* sb1  = (const float*)d_in[7];
    const float* sw2  = (const float*)d_in[8];
    const float* sb2  = (const float*)d_in[9];
    const float* pw1  = (const float*)d_in[10];
    const float* pb1  = (const float*)d_in[11];
    const float* pw2  = (const float*)d_in[12];
    const float* pb2  = (const float*)d_in[13];
    float* out = (float*)d_out;

    char* ws = (char*)d_ws;
    size_t off = 0;
    auto alloc = [&](size_t bytes) {
        void* p = ws + off;
        off += (bytes + 255) & ~(size_t)255;
        return p;
    };
    uint16_t* buf0 = (uint16_t*)alloc((size_t)2 * VV * 32 * 2);
    uint16_t* buf1 = (uint16_t*)alloc((size_t)2 * VV * 32 * 2);
    float* wT0     = (float*)alloc(27 * 32 * 4);
    uint16_t* wpk  = (uint16_t*)alloc((size_t)3 * 27 * 2 * 512 * 2);
    float2* spart  = (float2*)alloc((size_t)9216 * 2 * 32 * 8);
    float2* mr     = (float2*)alloc(4 * 64 * 8);
    float* rzone   = (float*)alloc((size_t)864 * 100 * 64 * 4);
    float* mzone   = (float*)alloc((size_t)864 * 100 * 4);
    float* roi     = (float*)alloc(2 * 100 * 32 * 4);
    (void)ws_size; (void)in_sizes; (void)n_in; (void)out_size;

    k_packw<<<328, 256, 0, stream>>>(w0, wk, wT0, wpk);

    dim3 cgrid(96, 96, 2);
    k_conv0<<<cgrid, 256, 0, stream>>>(data, wT0, buf0, spart);
    k_finalize<<<64, 256, 0, stream>>>((const float2*)spart, mr + 0);
    k_prepass_cl<<<2048, 256, 0, stream>>>(buf0, mr + 0);

    k_convk_mfma<0><<<2304, 512, 0, stream>>>(buf0, wpk + 0 * 27648, buf1, spart);
    k_finalize<<<64, 256, 0, stream>>>((const float2*)spart, mr + 64);
    k_prepass_cl<<<2048, 256, 0, stream>>>(buf1, mr + 64);

    k_convk_mfma<0><<<2304, 512, 0, stream>>>(buf1, wpk + 1 * 27648, buf0, spart);
    k_finalize<<<64, 256, 0, stream>>>((const float2*)spart, mr + 128);
    k_prepass_cl<<<2048, 256, 0, stream>>>(buf0, mr + 128);

    k_convk_mfma<1><<<2304, 512, 0, stream>>>(buf0, wpk + 2 * 27648, buf1, spart);
    k_finalize<<<64, 256, 0, stream>>>((const float2*)spart, mr + 192);

    k_pool_mfma<<<864, 448, 0, stream>>>(buf1, mask, mr + 192, rzone, mzone);
    k_roifin<<<100, 256, 0, stream>>>(rzone, mzone, roi);

    k_mlp<<<dim3(100, 2), 256, 0, stream>>>(roi, sw1, sb1, sw2, sb2,
                                            pw1, pb1, pw2, pb2, out);
}